// Round 1
// baseline (252.710 us; speedup 1.0000x reference)
//
#include <hip/hip_runtime.h>
#include <math.h>

#define BATCH 64
#define DIM   640
#define MSP   100        // spatial M = 10*10
#define TILE  64
#define NT    10         // DIM / TILE
#define NPAIR 55         // NT*(NT+1)/2  upper-tri tile pairs
#define PTRI  205120     // DIM*(DIM+1)/2
#define LS    101        // LDS row stride (odd mod 32 -> <=2-way conflicts, free)
#define EPSV  1e-5f

// ws layout (floats): [0,40960) d norms | [40960,81920) S row sums | [81920,81984) grand term
#define WS_D 0
#define WS_S (BATCH * DIM)
#define WS_G (2 * BATCH * DIM)

__global__ __launch_bounds__(256) void k_norms(const float* __restrict__ x,
                                               float* __restrict__ ws) {
    int row = blockIdx.x * 256 + threadIdx.x;      // 40960 rows total
    if (row >= BATCH * DIM) return;
    const float4* p4 = (const float4*)(x + (size_t)row * MSP);  // 400B rows -> 16B aligned
    float s = 0.f;
#pragma unroll
    for (int m = 0; m < MSP / 4; ++m) {
        float4 v = p4[m];
        s += v.x * v.x + v.y * v.y + v.z * v.z + v.w * v.w;
    }
    ws[WS_D + row] = s;
    ws[WS_S + row] = 0.f;   // ws is poisoned 0xAA each call -- must zero accumulators
}

__device__ __forceinline__ void decode_pair(int u, int& ti, int& tj) {
    ti = 0;
    while (u >= NT - ti) { u -= NT - ti; ++ti; }
    tj = ti + u;
}

// Shared Gram-tile computation: loads two 64x100 row blocks into LDS, computes
// 4x4 per-thread fp32 accumulators of G = Xi * Xj^T over K=100.
#define GRAM_TILE_BODY(pa, pb)                                                  \
    for (int idx = threadIdx.x; idx < TILE * MSP; idx += 256) {                 \
        int r = idx / MSP, m = idx - r * MSP;                                   \
        sA[r * LS + m] = (pa)[idx];                                             \
        sB[r * LS + m] = (pb)[idx];                                             \
    }

__global__ __launch_bounds__(256) void k_rowsums(const float* __restrict__ x,
                                                 const float* __restrict__ t,
                                                 float* __restrict__ ws) {
    __shared__ float sA[TILE * LS];
    __shared__ float sB[TILE * LS];
    __shared__ float sRow[TILE];
    __shared__ float sCol[TILE];

    int ti, tj;
    decode_pair(blockIdx.x, ti, tj);
    const int b = blockIdx.y;
    const int i0 = ti * TILE, j0 = tj * TILE;

    const float* pa = x + ((size_t)b * DIM + i0) * MSP;
    const float* pb = x + ((size_t)b * DIM + j0) * MSP;
    if (threadIdx.x < TILE) { sRow[threadIdx.x] = 0.f; sCol[threadIdx.x] = 0.f; }
    GRAM_TILE_BODY(pa, pb)
    __syncthreads();

    const int tx = threadIdx.x & 15, ty = threadIdx.x >> 4;
    const float* aB = sA + (4 * ty) * LS;
    const float* bB = sB + (4 * tx) * LS;
    float acc[4][4] = {};
#pragma unroll 4
    for (int k = 0; k < MSP; ++k) {
        float a0 = aB[k], a1 = aB[LS + k], a2 = aB[2 * LS + k], a3 = aB[3 * LS + k];
        float b0 = bB[k], b1 = bB[LS + k], b2 = bB[2 * LS + k], b3 = bB[3 * LS + k];
        acc[0][0] += a0 * b0; acc[0][1] += a0 * b1; acc[0][2] += a0 * b2; acc[0][3] += a0 * b3;
        acc[1][0] += a1 * b0; acc[1][1] += a1 * b1; acc[1][2] += a1 * b2; acc[1][3] += a1 * b3;
        acc[2][0] += a2 * b0; acc[2][1] += a2 * b1; acc[2][2] += a2 * b2; acc[2][3] += a2 * b3;
        acc[3][0] += a3 * b0; acc[3][1] += a3 * b1; acc[3][2] += a3 * b2; acc[3][3] += a3 * b3;
    }

    const float scale = expf(t[0]);
    const float* dn = ws + WS_D + b * DIM;
    float di[4], dj[4];
#pragma unroll
    for (int ii = 0; ii < 4; ++ii) di[ii] = dn[i0 + 4 * ty + ii];
#pragma unroll
    for (int jj = 0; jj < 4; ++jj) dj[jj] = dn[j0 + 4 * tx + jj];

    float rp[4] = {}, cp[4] = {};
#pragma unroll
    for (int ii = 0; ii < 4; ++ii)
#pragma unroll
        for (int jj = 0; jj < 4; ++jj) {
            float v = sqrtf(scale * fmaxf(di[ii] + dj[jj] - 2.f * acc[ii][jj], 0.f) + EPSV);
            rp[ii] += v; cp[jj] += v;
        }
#pragma unroll
    for (int ii = 0; ii < 4; ++ii) atomicAdd(&sRow[4 * ty + ii], rp[ii]);
#pragma unroll
    for (int jj = 0; jj < 4; ++jj) atomicAdd(&sCol[4 * tx + jj], cp[jj]);
    __syncthreads();

    float* S = ws + WS_S + b * DIM;
    if (threadIdx.x < TILE) {
        atomicAdd(&S[i0 + threadIdx.x], sRow[threadIdx.x]);
        if (ti != tj) atomicAdd(&S[j0 + threadIdx.x], sCol[threadIdx.x]);  // symmetry: col sums == row sums
    }
}

__global__ __launch_bounds__(256) void k_grand(float* __restrict__ ws) {
    const int b = blockIdx.x;
    const float* S = ws + WS_S + b * DIM;
    float s = 0.f;
    for (int i = threadIdx.x; i < DIM; i += 256) s += S[i];
#pragma unroll
    for (int off = 32; off > 0; off >>= 1) s += __shfl_down(s, off);
    __shared__ float red[4];
    if ((threadIdx.x & 63) == 0) red[threadIdx.x >> 6] = s;
    __syncthreads();
    if (threadIdx.x == 0)
        ws[WS_G + b] = (red[0] + red[1] + red[2] + red[3]) / ((float)DIM * (float)DIM);
}

__global__ __launch_bounds__(256) void k_out(const float* __restrict__ x,
                                             const float* __restrict__ t,
                                             const float* __restrict__ ws,
                                             float* __restrict__ out) {
    __shared__ float sA[TILE * LS];
    __shared__ float sB[TILE * LS];

    int ti, tj;
    decode_pair(blockIdx.x, ti, tj);
    const int b = blockIdx.y;
    const int i0 = ti * TILE, j0 = tj * TILE;

    const float* pa = x + ((size_t)b * DIM + i0) * MSP;
    const float* pb = x + ((size_t)b * DIM + j0) * MSP;
    GRAM_TILE_BODY(pa, pb)
    __syncthreads();

    const int tx = threadIdx.x & 15, ty = threadIdx.x >> 4;
    const float* aB = sA + (4 * ty) * LS;
    const float* bB = sB + (4 * tx) * LS;
    float acc[4][4] = {};
#pragma unroll 4
    for (int k = 0; k < MSP; ++k) {
        float a0 = aB[k], a1 = aB[LS + k], a2 = aB[2 * LS + k], a3 = aB[3 * LS + k];
        float b0 = bB[k], b1 = bB[LS + k], b2 = bB[2 * LS + k], b3 = bB[3 * LS + k];
        acc[0][0] += a0 * b0; acc[0][1] += a0 * b1; acc[0][2] += a0 * b2; acc[0][3] += a0 * b3;
        acc[1][0] += a1 * b0; acc[1][1] += a1 * b1; acc[1][2] += a1 * b2; acc[1][3] += a1 * b3;
        acc[2][0] += a2 * b0; acc[2][1] += a2 * b1; acc[2][2] += a2 * b2; acc[2][3] += a2 * b3;
        acc[3][0] += a3 * b0; acc[3][1] += a3 * b1; acc[3][2] += a3 * b2; acc[3][3] += a3 * b3;
    }

    const float scale = expf(t[0]);
    const float inv = 1.f / (float)DIM;
    const float* dn = ws + WS_D + b * DIM;
    const float* S  = ws + WS_S + b * DIM;
    const float gterm = ws[WS_G + b];

    float di[4], dj[4], si[4], sj[4];
#pragma unroll
    for (int ii = 0; ii < 4; ++ii) { int i = i0 + 4 * ty + ii; di[ii] = dn[i]; si[ii] = S[i] * inv; }
#pragma unroll
    for (int jj = 0; jj < 4; ++jj) { int j = j0 + 4 * tx + jj; dj[jj] = dn[j]; sj[jj] = S[j] * inv; }

    float* outb = out + (size_t)b * PTRI;
#pragma unroll
    for (int ii = 0; ii < 4; ++ii) {
        const int i = i0 + 4 * ty + ii;
        const int base = i * DIM - (i * (i - 1)) / 2 - i;   // triu row offset minus i
#pragma unroll
        for (int jj = 0; jj < 4; ++jj) {
            const int j = j0 + 4 * tx + jj;
            if (j >= i) {
                float v = sqrtf(scale * fmaxf(di[ii] + dj[jj] - 2.f * acc[ii][jj], 0.f) + EPSV);
                outb[base + j] = v - si[ii] - sj[jj] + gterm;
            }
        }
    }
}

extern "C" void kernel_launch(void* const* d_in, const int* in_sizes, int n_in,
                              void* d_out, int out_size, void* d_ws, size_t ws_size,
                              hipStream_t stream) {
    const float* x = (const float*)d_in[0];
    const float* t = (const float*)d_in[1];
    float* out = (float*)d_out;
    float* ws  = (float*)d_ws;   // needs 81984 floats = 328 KB

    k_norms  <<<dim3((BATCH * DIM + 255) / 256), 256, 0, stream>>>(x, ws);
    k_rowsums<<<dim3(NPAIR, BATCH),              256, 0, stream>>>(x, t, ws);
    k_grand  <<<dim3(BATCH),                     256, 0, stream>>>(ws);
    k_out    <<<dim3(NPAIR, BATCH),              256, 0, stream>>>(x, t, ws, out);
}

// Round 2
// 155.340 us; speedup vs baseline: 1.6268x; 1.6268x over previous
//
#include <hip/hip_runtime.h>
#include <math.h>

#define BATCH 64
#define DIM   640
#define MSP   100        // spatial M = 10*10
#define TILE  64
#define NT    10         // DIM / TILE
#define NPAIR 55         // NT*(NT+1)/2  upper-tri tile pairs
#define PTRI  205120     // DIM*(DIM+1)/2
#define KP    128        // K padded to multiple of 32 for MFMA
#define LSB   136        // LDS row stride in bf16 elems (KP+8): 272B -> +4 banks/row, 2-way = free
#define EPSV  1e-5f

// ws layout (floats): [0,40960) d norms | [40960,81920) S row sums | [81920,81984) grand term
#define WS_D 0
#define WS_S (BATCH * DIM)
#define WS_G (2 * BATCH * DIM)

typedef __attribute__((ext_vector_type(8))) short short8;
typedef __attribute__((ext_vector_type(4))) float f32x4;

// RNE float -> bf16 bits
__device__ __forceinline__ short f2bf(float f) {
    union { float f; unsigned u; } x; x.f = f;
    unsigned r = x.u + 0x7fffu + ((x.u >> 16) & 1u);
    return (short)(r >> 16);
}
__device__ __forceinline__ float bf2f(short h) {
    union { unsigned u; float f; } x; x.u = ((unsigned)(unsigned short)h) << 16;
    return x.f;
}

// norms MUST be computed from bf16-rounded x so that d_i + d_i - 2*G_ii == 0
// exactly on the diagonal (G comes from bf16 MFMA).
__global__ __launch_bounds__(256) void k_norms(const float* __restrict__ x,
                                               float* __restrict__ ws) {
    int row = blockIdx.x * 256 + threadIdx.x;      // 40960 rows total
    if (row >= BATCH * DIM) return;
    const float4* p4 = (const float4*)(x + (size_t)row * MSP);  // 400B rows, 16B aligned
    float s = 0.f;
#pragma unroll
    for (int m = 0; m < MSP / 4; ++m) {
        float4 v = p4[m];
        float a = bf2f(f2bf(v.x)), b = bf2f(f2bf(v.y));
        float c = bf2f(f2bf(v.z)), d = bf2f(f2bf(v.w));
        s += a * a + b * b + c * c + d * d;
    }
    ws[WS_D + row] = s;
    ws[WS_S + row] = 0.f;   // ws is poisoned 0xAA each call -- zero accumulators
}

__device__ __forceinline__ void decode_pair(int u, int& ti, int& tj) {
    ti = 0;
    while (u >= NT - ti) { u -= NT - ti; ++ti; }
    tj = ti + u;
}

// Stage one 64x100 fp32 row-block into LDS as bf16, K zero-padded to 128.
__device__ __forceinline__ void stage_tile(const float* __restrict__ p,
                                           short* __restrict__ s, int tid) {
    const float4* p4 = (const float4*)p;           // 1600 float4 per tile
    for (int idx = tid; idx < 1600; idx += 256) {
        int row = idx / 25, c4 = idx - row * 25;   // 25 float4 per 100-float row
        float4 v = p4[idx];
        short4 h;
        h.x = f2bf(v.x); h.y = f2bf(v.y); h.z = f2bf(v.z); h.w = f2bf(v.w);
        *(short4*)(s + row * LSB + c4 * 4) = h;    // 8B-aligned ds_write_b64
    }
    for (int idx = tid; idx < TILE * 7; idx += 256) {  // zero k=100..127 (28 bf16 = 7 short4)
        int row = idx / 7, c = idx - row * 7;
        short4 z; z.x = 0; z.y = 0; z.z = 0; z.w = 0;
        *(short4*)(s + row * LSB + 100 + c * 4) = z;
    }
}

// Per-wave 32x32 quadrant via 2x2 mfma_f32_16x16x32_bf16.
// A/B frag: lane reads row (m or n) = base + (lane&15), k = ks*32 + (lane>>4)*8.
// C/D: col = lane&15, row = (lane>>4)*4 + reg.
#define GRAM_MFMA(acc)                                                          \
    {                                                                           \
        const short* aBase = sA + (r0 + lm) * LSB;                              \
        const short* bBase = sB + (c0 + lm) * LSB;                              \
        _Pragma("unroll")                                                       \
        for (int ks = 0; ks < 4; ++ks) {                                        \
            int ko = ks * 32 + lq * 8;                                          \
            short8 a0 = *(const short8*)(aBase + ko);                           \
            short8 a1 = *(const short8*)(aBase + 16 * LSB + ko);                \
            short8 b0 = *(const short8*)(bBase + ko);                           \
            short8 b1 = *(const short8*)(bBase + 16 * LSB + ko);                \
            acc[0][0] = __builtin_amdgcn_mfma_f32_16x16x32_bf16(a0, b0, acc[0][0], 0, 0, 0); \
            acc[0][1] = __builtin_amdgcn_mfma_f32_16x16x32_bf16(a0, b1, acc[0][1], 0, 0, 0); \
            acc[1][0] = __builtin_amdgcn_mfma_f32_16x16x32_bf16(a1, b0, acc[1][0], 0, 0, 0); \
            acc[1][1] = __builtin_amdgcn_mfma_f32_16x16x32_bf16(a1, b1, acc[1][1], 0, 0, 0); \
        }                                                                       \
    }

__global__ __launch_bounds__(256) void k_rowsums(const float* __restrict__ x,
                                                 const float* __restrict__ t,
                                                 float* __restrict__ ws) {
    __shared__ short sA[TILE * LSB];
    __shared__ short sB[TILE * LSB];
    __shared__ float sRow[TILE];
    __shared__ float sCol[TILE];

    int ti, tj;
    decode_pair(blockIdx.x, ti, tj);
    const int b = blockIdx.y;
    const int i0 = ti * TILE, j0 = tj * TILE;
    const int tid = threadIdx.x;

    if (tid < TILE) { sRow[tid] = 0.f; sCol[tid] = 0.f; }
    stage_tile(x + ((size_t)b * DIM + i0) * MSP, sA, tid);
    stage_tile(x + ((size_t)b * DIM + j0) * MSP, sB, tid);
    __syncthreads();

    const int wave = tid >> 6, lane = tid & 63;
    const int lm = lane & 15, lq = lane >> 4;
    const int r0 = (wave >> 1) * 32, c0 = (wave & 1) * 32;

    f32x4 acc[2][2] = {};
    GRAM_MFMA(acc)

    const float scale = expf(t[0]);
    const float* dn = ws + WS_D + b * DIM;
    float di[2][4], dj[2];
#pragma unroll
    for (int a = 0; a < 2; ++a)
#pragma unroll
        for (int r = 0; r < 4; ++r) di[a][r] = dn[i0 + r0 + 16 * a + lq * 4 + r];
#pragma unroll
    for (int bb = 0; bb < 2; ++bb) dj[bb] = dn[j0 + c0 + 16 * bb + lm];

    float rp[2][4] = {}, cp[2] = {};
#pragma unroll
    for (int a = 0; a < 2; ++a)
#pragma unroll
        for (int bb = 0; bb < 2; ++bb)
#pragma unroll
            for (int r = 0; r < 4; ++r) {
                float v = sqrtf(scale * fmaxf(di[a][r] + dj[bb] - 2.f * acc[a][bb][r], 0.f) + EPSV);
                rp[a][r] += v; cp[bb] += v;
            }

    // row sums: butterfly over lm (cols), lane lm==0 commits
#pragma unroll
    for (int a = 0; a < 2; ++a)
#pragma unroll
        for (int r = 0; r < 4; ++r) {
            float v = rp[a][r];
            v += __shfl_xor(v, 1); v += __shfl_xor(v, 2);
            v += __shfl_xor(v, 4); v += __shfl_xor(v, 8);
            if (lm == 0) atomicAdd(&sRow[r0 + 16 * a + lq * 4 + r], v);
        }
    // col sums: butterfly over lq (rows), lanes 0..15 commit
#pragma unroll
    for (int bb = 0; bb < 2; ++bb) {
        float v = cp[bb];
        v += __shfl_xor(v, 16); v += __shfl_xor(v, 32);
        if (lq == 0) atomicAdd(&sCol[c0 + 16 * bb + lm], v);
    }
    __syncthreads();

    float* S = ws + WS_S + b * DIM;
    if (tid < TILE) {
        atomicAdd(&S[i0 + tid], sRow[tid]);
        if (ti != tj) atomicAdd(&S[j0 + tid], sCol[tid]);  // symmetry: col sums == row sums
    }
}

__global__ __launch_bounds__(256) void k_grand(float* __restrict__ ws) {
    const int b = blockIdx.x;
    const float* S = ws + WS_S + b * DIM;
    float s = 0.f;
    for (int i = threadIdx.x; i < DIM; i += 256) s += S[i];
#pragma unroll
    for (int off = 32; off > 0; off >>= 1) s += __shfl_down(s, off);
    __shared__ float red[4];
    if ((threadIdx.x & 63) == 0) red[threadIdx.x >> 6] = s;
    __syncthreads();
    if (threadIdx.x == 0)
        ws[WS_G + b] = (red[0] + red[1] + red[2] + red[3]) / ((float)DIM * (float)DIM);
}

__global__ __launch_bounds__(256) void k_out(const float* __restrict__ x,
                                             const float* __restrict__ t,
                                             const float* __restrict__ ws,
                                             float* __restrict__ out) {
    __shared__ short sA[TILE * LSB];
    __shared__ short sB[TILE * LSB];

    int ti, tj;
    decode_pair(blockIdx.x, ti, tj);
    const int b = blockIdx.y;
    const int i0 = ti * TILE, j0 = tj * TILE;
    const int tid = threadIdx.x;

    stage_tile(x + ((size_t)b * DIM + i0) * MSP, sA, tid);
    stage_tile(x + ((size_t)b * DIM + j0) * MSP, sB, tid);
    __syncthreads();

    const int wave = tid >> 6, lane = tid & 63;
    const int lm = lane & 15, lq = lane >> 4;
    const int r0 = (wave >> 1) * 32, c0 = (wave & 1) * 32;

    f32x4 acc[2][2] = {};
    GRAM_MFMA(acc)

    const float scale = expf(t[0]);
    const float inv = 1.f / (float)DIM;
    const float* dn = ws + WS_D + b * DIM;
    const float* S  = ws + WS_S + b * DIM;
    const float gterm = ws[WS_G + b];

    float di[2][4], si[2][4], dj[2], sj[2];
#pragma unroll
    for (int a = 0; a < 2; ++a)
#pragma unroll
        for (int r = 0; r < 4; ++r) {
            int i = i0 + r0 + 16 * a + lq * 4 + r;
            di[a][r] = dn[i]; si[a][r] = S[i] * inv;
        }
#pragma unroll
    for (int bb = 0; bb < 2; ++bb) {
        int j = j0 + c0 + 16 * bb + lm;
        dj[bb] = dn[j]; sj[bb] = S[j] * inv;
    }

    float* outb = out + (size_t)b * PTRI;
#pragma unroll
    for (int a = 0; a < 2; ++a)
#pragma unroll
        for (int r = 0; r < 4; ++r) {
            const int i = i0 + r0 + 16 * a + lq * 4 + r;
            const int base = i * DIM - (i * (i - 1)) / 2 - i;   // triu row offset minus i
#pragma unroll
            for (int bb = 0; bb < 2; ++bb) {
                const int j = j0 + c0 + 16 * bb + lm;
                if (j >= i) {
                    float v = sqrtf(scale * fmaxf(di[a][r] + dj[bb] - 2.f * acc[a][bb][r], 0.f) + EPSV);
                    outb[base + j] = v - si[a][r] - sj[bb] + gterm;
                }
            }
        }
}

extern "C" void kernel_launch(void* const* d_in, const int* in_sizes, int n_in,
                              void* d_out, int out_size, void* d_ws, size_t ws_size,
                              hipStream_t stream) {
    const float* x = (const float*)d_in[0];
    const float* t = (const float*)d_in[1];
    float* out = (float*)d_out;
    float* ws  = (float*)d_ws;   // needs 81984 floats = 328 KB

    k_norms  <<<dim3((BATCH * DIM + 255) / 256), 256, 0, stream>>>(x, ws);
    k_rowsums<<<dim3(NPAIR, BATCH),              256, 0, stream>>>(x, t, ws);
    k_grand  <<<dim3(BATCH),                     256, 0, stream>>>(ws);
    k_out    <<<dim3(NPAIR, BATCH),              256, 0, stream>>>(x, t, ws, out);
}

// Round 3
// 138.653 us; speedup vs baseline: 1.8226x; 1.1204x over previous
//
#include <hip/hip_runtime.h>
#include <math.h>

#define BATCH 64
#define DIM   640
#define MSP   100        // spatial M = 10*10
#define TILE  64
#define NT    10         // DIM / TILE
#define NPAIR 55         // NT*(NT+1)/2 upper-tri tile pairs
#define PTRI  205120     // DIM*(DIM+1)/2
#define KP    128        // K padded to multiple of 32 for MFMA
#define LSB   136        // staging LDS row stride (bf16 elems): 272B/row -> 2-way max, free
#define LST   68         // transpose LDS row stride (fp16 elems): 136B/row, 8B-aligned rows
#define EPSV  1e-5f

// ws float-region offsets (floats)
#define WS_D 0
#define WS_S 40960
#define WS_G 81920
// ws byte offsets (float region ends at 81984*4 = 327936, already 256B-aligned)
#define XB_OFF 327936ull      // bf16 x, K padded to 128: 64*640*128 shorts = 10,485,760 B
#define TI_OFF 10813696ull    // fp16 dcov tiles: 64*55*4096 halves  = 28,835,840 B
// total ws needed: 39,649,536 B (~39.6 MB)

typedef __attribute__((ext_vector_type(8))) short short8;
typedef __attribute__((ext_vector_type(4))) float f32x4;
typedef _Float16 half_t;
typedef __attribute__((ext_vector_type(4))) _Float16 half4;

__device__ __forceinline__ short f2bf(float f) {
    union { float f; unsigned u; } x; x.f = f;
    unsigned r = x.u + 0x7fffu + ((x.u >> 16) & 1u);
    return (short)(r >> 16);
}
__device__ __forceinline__ float bf2f(short h) {
    union { unsigned u; float f; } x; x.u = ((unsigned)(unsigned short)h) << 16;
    return x.f;
}

// One pass over x: bf16-convert (RNE), pad K 100->128 with zeros, store xb;
// norms from the ROUNDED values (so diag d_i+d_i-2*G_ii cancels exactly vs
// bf16 MFMA Gram); zero the S accumulators (ws is poisoned 0xAA each call).
__global__ __launch_bounds__(256) void k_prep(const float* __restrict__ x,
                                              float* __restrict__ ws) {
    short* xb = (short*)((char*)ws + XB_OFF);
    const int t = threadIdx.x;
    const int rr = t >> 4, c = t & 15;
    const int row = blockIdx.x * 16 + rr;          // 0..40959
    const int k0 = c * 8;
    const float* src = x + (size_t)row * MSP;

    float v[8];
#pragma unroll
    for (int e = 0; e < 8; ++e) v[e] = 0.f;
    if (k0 <= 88) {                                // k0..k0+7 all < 100
        float4 u0 = *(const float4*)(src + k0);
        float4 u1 = *(const float4*)(src + k0 + 4);
        v[0] = u0.x; v[1] = u0.y; v[2] = u0.z; v[3] = u0.w;
        v[4] = u1.x; v[5] = u1.y; v[6] = u1.z; v[7] = u1.w;
    } else if (k0 == 96) {                         // only 96..99 valid (no OOB read)
        float4 u0 = *(const float4*)(src + 96);
        v[0] = u0.x; v[1] = u0.y; v[2] = u0.z; v[3] = u0.w;
    }                                              // k0 >= 104: zeros

    short8 h; float s = 0.f;
#pragma unroll
    for (int e = 0; e < 8; ++e) {
        short hb = f2bf(v[e]);
        float vr = bf2f(hb);
        s += vr * vr;
        h[e] = hb;
    }
    *(short8*)(xb + (size_t)row * KP + k0) = h;    // 16B stores, lanes contiguous

    // reduce norm over the 16 lanes of this row (within-wave xor masks 1..8)
    s += __shfl_xor(s, 1); s += __shfl_xor(s, 2);
    s += __shfl_xor(s, 4); s += __shfl_xor(s, 8);
    if (c == 0) { ws[WS_D + row] = s; ws[WS_S + row] = 0.f; }
}

__device__ __forceinline__ void decode_pair(int u, int& ti, int& tj) {
    ti = 0;
    while (u >= NT - ti) { u -= NT - ti; ++ti; }
    tj = ti + u;
}

// Per-wave 32x32 quadrant via 2x2 mfma_f32_16x16x32_bf16.
// A/B frag: lane reads row = base + (lane&15), k = ks*32 + (lane>>4)*8.
// C/D: col = lane&15, row = (lane>>4)*4 + reg.
#define GRAM_MFMA(acc)                                                          \
    {                                                                           \
        const short* aBase = sA + (r0 + lm) * LSB;                              \
        const short* bBase = sB + (c0 + lm) * LSB;                              \
        _Pragma("unroll")                                                       \
        for (int ks = 0; ks < 4; ++ks) {                                        \
            int ko = ks * 32 + lq * 8;                                          \
            short8 a0 = *(const short8*)(aBase + ko);                           \
            short8 a1 = *(const short8*)(aBase + 16 * LSB + ko);                \
            short8 b0 = *(const short8*)(bBase + ko);                           \
            short8 b1 = *(const short8*)(bBase + 16 * LSB + ko);                \
            acc[0][0] = __builtin_amdgcn_mfma_f32_16x16x32_bf16(a0, b0, acc[0][0], 0, 0, 0); \
            acc[0][1] = __builtin_amdgcn_mfma_f32_16x16x32_bf16(a0, b1, acc[0][1], 0, 0, 0); \
            acc[1][0] = __builtin_amdgcn_mfma_f32_16x16x32_bf16(a1, b0, acc[1][0], 0, 0, 0); \
            acc[1][1] = __builtin_amdgcn_mfma_f32_16x16x32_bf16(a1, b1, acc[1][1], 0, 0, 0); \
        }                                                                       \
    }

// Single GEMM pass: Gram tile -> sqrt-dcov -> row/col sums (shuffle+atomics)
// -> fp16 tile (row-major, via LDS transpose reusing the staging buffer).
__global__ __launch_bounds__(256) void k_gram(const float* __restrict__ tsc,
                                              float* __restrict__ ws) {
    __shared__ short sAB[2 * TILE * LSB];          // 34,816 B; reused for transpose
    __shared__ float sRow[TILE];
    __shared__ float sCol[TILE];
    short* sA = sAB;
    short* sB = sAB + TILE * LSB;

    int ti, tj;
    decode_pair(blockIdx.x, ti, tj);
    const int b = blockIdx.y;
    const int i0 = ti * TILE, j0 = tj * TILE;
    const int tid = threadIdx.x;
    const short* xb = (const short*)((const char*)ws + XB_OFF);

    if (tid < TILE) { sRow[tid] = 0.f; sCol[tid] = 0.f; }
    {
        const short* pa = xb + ((size_t)(b * DIM + i0)) * KP;
        const short* pb = xb + ((size_t)(b * DIM + j0)) * KP;
#pragma unroll
        for (int it = 0; it < 4; ++it) {
            int idx = tid + it * 256;              // 0..1023
            int row = idx >> 4, c8 = (idx & 15) * 8;
            *(short8*)(sA + row * LSB + c8) = *(const short8*)(pa + row * KP + c8);
            *(short8*)(sB + row * LSB + c8) = *(const short8*)(pb + row * KP + c8);
        }
    }
    __syncthreads();

    const int wave = tid >> 6, lane = tid & 63;
    const int lm = lane & 15, lq = lane >> 4;
    const int r0 = (wave >> 1) * 32, c0 = (wave & 1) * 32;

    f32x4 acc[2][2] = {};
    GRAM_MFMA(acc)

    const float scale = expf(tsc[0]);
    const float* dn = ws + WS_D + b * DIM;
    float di[2][4], dj[2];
#pragma unroll
    for (int a = 0; a < 2; ++a)
#pragma unroll
        for (int r = 0; r < 4; ++r) di[a][r] = dn[i0 + r0 + 16 * a + lq * 4 + r];
#pragma unroll
    for (int bb = 0; bb < 2; ++bb) dj[bb] = dn[j0 + c0 + 16 * bb + lm];

    float vv[2][2][4];
    float rp[2][4] = {}, cp[2] = {};
#pragma unroll
    for (int a = 0; a < 2; ++a)
#pragma unroll
        for (int bb = 0; bb < 2; ++bb)
#pragma unroll
            for (int r = 0; r < 4; ++r) {
                float v = sqrtf(scale * fmaxf(di[a][r] + dj[bb] - 2.f * acc[a][bb][r], 0.f) + EPSV);
                vv[a][bb][r] = v;
                rp[a][r] += v; cp[bb] += v;
            }

#pragma unroll
    for (int a = 0; a < 2; ++a)
#pragma unroll
        for (int r = 0; r < 4; ++r) {
            float v = rp[a][r];
            v += __shfl_xor(v, 1); v += __shfl_xor(v, 2);
            v += __shfl_xor(v, 4); v += __shfl_xor(v, 8);
            if (lm == 0) atomicAdd(&sRow[r0 + 16 * a + lq * 4 + r], v);
        }
#pragma unroll
    for (int bb = 0; bb < 2; ++bb) {
        float v = cp[bb];
        v += __shfl_xor(v, 16); v += __shfl_xor(v, 32);
        if (lq == 0) atomicAdd(&sCol[c0 + 16 * bb + lm], v);
    }
    __syncthreads();   // sums done AND all MFMA ds_reads of sA/sB done

    float* S = ws + WS_S + b * DIM;
    if (tid < TILE) {
        atomicAdd(&S[i0 + tid], sRow[tid]);
        if (ti != tj) atomicAdd(&S[j0 + tid], sCol[tid]);  // symmetry: col==row sums
    }

    // transpose dcov tile through LDS (reuse staging region) -> row-major fp16
    half_t* ldsT = (half_t*)sAB;                   // 64 x LST(68), 8704 B
#pragma unroll
    for (int a = 0; a < 2; ++a)
#pragma unroll
        for (int bb = 0; bb < 2; ++bb)
#pragma unroll
            for (int r = 0; r < 4; ++r) {
                int row = r0 + 16 * a + lq * 4 + r;
                int col = c0 + 16 * bb + lm;
                ldsT[row * LST + col] = (half_t)vv[a][bb][r];
            }
    __syncthreads();

    half_t* tb = (half_t*)((char*)ws + TI_OFF) + ((size_t)(b * NPAIR + blockIdx.x) << 12);
#pragma unroll
    for (int it = 0; it < 4; ++it) {
        int chunk = tid + it * 256;                // 0..1023 (4 fp16 each)
        int ri = chunk >> 4, c4 = (chunk & 15) * 4;
        *(half4*)(tb + ri * 64 + c4) = *(const half4*)(ldsT + ri * LST + c4);
    }
}

__global__ __launch_bounds__(256) void k_grand(float* __restrict__ ws) {
    const int b = blockIdx.x;
    const float* S = ws + WS_S + b * DIM;
    float s = 0.f;
    for (int i = threadIdx.x; i < DIM; i += 256) s += S[i];
#pragma unroll
    for (int off = 32; off > 0; off >>= 1) s += __shfl_down(s, off);
    __shared__ float red[4];
    if ((threadIdx.x & 63) == 0) red[threadIdx.x >> 6] = s;
    __syncthreads();
    if (threadIdx.x == 0)
        ws[WS_G + b] = (red[0] + red[1] + red[2] + red[3]) / ((float)DIM * (float)DIM);
}

// Streaming centering + triu pack: read fp16 tiles, write fp32 output.
// grid (ti, b, half): block covers rows [ti*64 + z*32, +32), cols j >= i.
__global__ __launch_bounds__(256) void k_final(const float* __restrict__ ws,
                                               float* __restrict__ out) {
    const int ti = blockIdx.x;
    const int b  = blockIdx.y;
    const int zz = blockIdx.z;
    const int ntj = NT - ti;
    const int lane = threadIdx.x & 63;
    const int segq = threadIdx.x >> 6;             // 0..3
    const float inv = 1.f / (float)DIM;
    const float* S = ws + WS_S + b * DIM;
    const float g = ws[WS_G + b];
    const int pbase = ti * NT - (ti * (ti - 1)) / 2;  // pair index of (ti,ti)
    const half_t* tiles = (const half_t*)((const char*)ws + TI_OFF);
    float* outb = out + (size_t)b * PTRI;

    const int nseg = 32 * ntj;                     // segments: (tjo, rr), 64 cols each
    for (int s = segq; s < nseg; s += 4) {
        int tjo = s >> 5;
        int rr  = s & 31;
        int ri  = zz * 32 + rr;
        int i   = ti * TILE + ri;
        int j   = (ti + tjo) * TILE + lane;
        const half_t* tb = tiles + ((size_t)(b * NPAIR + pbase + tjo) << 12);
        float v = (float)tb[ri * 64 + lane];
        if (j >= i) {
            int base = i * DIM - (i * (i - 1)) / 2 - i;
            outb[base + j] = v - (S[i] + S[j]) * inv + g;
        }
    }
}

extern "C" void kernel_launch(void* const* d_in, const int* in_sizes, int n_in,
                              void* d_out, int out_size, void* d_ws, size_t ws_size,
                              hipStream_t stream) {
    const float* x = (const float*)d_in[0];
    const float* t = (const float*)d_in[1];
    float* out = (float*)d_out;
    float* ws  = (float*)d_ws;   // needs ~39.6 MB (see layout at top)

    k_prep <<<dim3(BATCH * DIM / 16), 256, 0, stream>>>(x, ws);
    k_gram <<<dim3(NPAIR, BATCH),     256, 0, stream>>>(t, ws);
    k_grand<<<dim3(BATCH),            256, 0, stream>>>(ws);
    k_final<<<dim3(NT, BATCH, 2),     256, 0, stream>>>(ws, out);
}